// Round 1
// baseline (84.558 us; speedup 1.0000x reference)
//
#include <hip/hip_runtime.h>
#include <math.h>

#define BDIM 8
#define SDIM 2048
#define EDIM 512
#define LDIM 128
#define MTOT (BDIM * SDIM)   // 16384
#define TM 32                // rows per block
#define BK 64                // k-chunk
#define PAD 8                // shorts of padding per LDS row
#define LSTR (BK + PAD)      // 72 shorts = 144 B row stride (16B-aligned, 2-way conflicts max)

typedef __attribute__((ext_vector_type(8))) short s8v;    // 8 bf16 (4 VGPRs) MFMA frag
typedef __attribute__((ext_vector_type(4))) float f4v;

__device__ __forceinline__ unsigned short f2bf(float x) {
    union { float f; unsigned u; } c; c.f = x;
    return (unsigned short)((c.u + 0x7fffu + ((c.u >> 16) & 1u)) >> 16);  // RNE
}

// ---- prep: Bmat(bf16, [L][E] = B^T layout), m2[l], inv_var, coef ----
__global__ __launch_bounds__(64) void gs_prep(
    const float* __restrict__ means, const float* __restrict__ var,
    unsigned short* __restrict__ Bmat, float* __restrict__ m2,
    float* __restrict__ ivbuf, float* __restrict__ coef)
{
    const int l = blockIdx.x;    // 0..127
    const int t = threadIdx.x;   // 0..63
    const int e0 = t * 8;

    float mv[8], iv[8];
    const float* mrow = means + l * EDIM + e0;
#pragma unroll
    for (int i = 0; i < 8; ++i) { mv[i] = mrow[i]; iv[i] = 1.0f / var[e0 + i]; }

    float part = 0.0f;
    s8v pr;
#pragma unroll
    for (int i = 0; i < 8; ++i) {
        float p = mv[i] * iv[i];            // means * inv_var
        pr[i] = (short)f2bf(p);
        part += mv[i] * p;                  // means^2 * inv_var
    }
    *(s8v*)(Bmat + l * EDIM + e0) = pr;

#pragma unroll
    for (int off = 32; off > 0; off >>= 1) part += __shfl_down(part, off, 64);
    if (t == 0) m2[l] = part;

    if (l == 0) {
#pragma unroll
        for (int i = 0; i < 8; ++i) ivbuf[e0 + i] = iv[i];
        float ld = 0.0f;
#pragma unroll
        for (int i = 0; i < 8; ++i) ld += logf(var[e0 + i]);
#pragma unroll
        for (int off = 32; off > 0; off >>= 1) ld += __shfl_down(ld, off, 64);
        if (t == 0) {
            const float factor = -(float)EDIM * 0.5f * 1.8378770664093453f; // ln(2*pi)
            *coef = factor - 0.5f * ld;
        }
    }
}

// ---- main: M=16384 x N=128 x K=512 bf16 MFMA GEMM + rank-1 corrections ----
__global__ __launch_bounds__(256) void gs_main(
    const float* __restrict__ emb, const unsigned short* __restrict__ Bmat,
    const float* __restrict__ m2, const float* __restrict__ ivbuf,
    const float* __restrict__ coef, float* __restrict__ out)
{
    __shared__ __align__(16) unsigned short Alds[TM][LSTR];    // 32x72 shorts
    __shared__ __align__(16) unsigned short Blds[LDIM][LSTR];  // 128x72 shorts
    __shared__ float e2part[256];
    __shared__ float e2s[TM];

    const int t    = threadIdx.x;
    const int lane = t & 63;
    const int wave = t >> 6;
    const int m0   = blockIdx.x * TM;

    // staging map: thread covers (arow, kseg..kseg+7)
    const int arow = t >> 3;           // 0..31
    const int kseg = (t & 7) * 8;      // 0..56

    // compute map: wave grid 2x2 over 32 rows x 128 cols
    const int r0w  = (wave >> 1) * 16;
    const int c0w  = (wave & 1) * 64;
    const int frow = lane & 15;
    const int fk   = (lane >> 4) * 8;

    f4v acc[4];
#pragma unroll
    for (int i = 0; i < 4; ++i) acc[i] = (f4v)0.0f;

    float e2acc = 0.0f;
    const float* embp = emb + (m0 + arow) * EDIM + kseg;
    const unsigned short* bp = Bmat + arow * EDIM + kseg;   // arow doubles as brow0

    for (int kc = 0; kc < EDIM / BK; ++kc) {
        const int k0 = kc * BK;
        // issue global loads
        f4v x0 = *(const f4v*)(embp + k0);
        f4v x1 = *(const f4v*)(embp + k0 + 4);
        f4v v0 = *(const f4v*)(ivbuf + k0 + kseg);
        f4v v1 = *(const f4v*)(ivbuf + k0 + kseg + 4);
        s8v b0 = *(const s8v*)(bp + (0 * 32) * EDIM + k0);
        s8v b1 = *(const s8v*)(bp + (1 * 32) * EDIM + k0);
        s8v b2 = *(const s8v*)(bp + (2 * 32) * EDIM + k0);
        s8v b3 = *(const s8v*)(bp + (3 * 32) * EDIM + k0);

        // convert + fused e2 while other loads in flight
        s8v a8;
#pragma unroll
        for (int i = 0; i < 4; ++i) {
            a8[i] = (short)f2bf(x0[i]);
            e2acc += x0[i] * x0[i] * v0[i];
        }
#pragma unroll
        for (int i = 0; i < 4; ++i) {
            a8[4 + i] = (short)f2bf(x1[i]);
            e2acc += x1[i] * x1[i] * v1[i];
        }

        __syncthreads();   // prior iter's LDS reads done
        *(s8v*)&Alds[arow][kseg] = a8;
        *(s8v*)&Blds[arow +  0][kseg] = b0;
        *(s8v*)&Blds[arow + 32][kseg] = b1;
        *(s8v*)&Blds[arow + 64][kseg] = b2;
        *(s8v*)&Blds[arow + 96][kseg] = b3;
        __syncthreads();

#pragma unroll
        for (int ks = 0; ks < BK; ks += 32) {
            s8v af = *(const s8v*)&Alds[r0w + frow][ks + fk];
#pragma unroll
            for (int ct = 0; ct < 4; ++ct) {
                s8v bfv = *(const s8v*)&Blds[c0w + ct * 16 + frow][ks + fk];
                acc[ct] = __builtin_amdgcn_mfma_f32_16x16x32_bf16(af, bfv, acc[ct], 0, 0, 0);
            }
        }
    }

    // reduce e2 partials: row r lives in threads 8r..8r+7
    e2part[t] = e2acc;
    __syncthreads();
    if (t < TM) {
        float s = 0.0f;
#pragma unroll
        for (int j = 0; j < 8; ++j) s += e2part[t * 8 + j];
        e2s[t] = s;
    }
    __syncthreads();

    const float cf = *coef;
#pragma unroll
    for (int ct = 0; ct < 4; ++ct) {
        const int n = c0w + ct * 16 + frow;
        const float cm = cf - 0.5f * m2[n];
#pragma unroll
        for (int r = 0; r < 4; ++r) {
            const int row = r0w + (lane >> 4) * 4 + r;   // C/D: col=lane&15, row=quad*4+reg
            out[(m0 + row) * LDIM + n] = acc[ct][r] + cm - 0.5f * e2s[row];
        }
    }
}

extern "C" void kernel_launch(void* const* d_in, const int* in_sizes, int n_in,
                              void* d_out, int out_size, void* d_ws, size_t ws_size,
                              hipStream_t stream) {
    const float* emb   = (const float*)d_in[0];
    const float* means = (const float*)d_in[1];
    const float* var   = (const float*)d_in[2];
    float* out = (float*)d_out;

    char* ws = (char*)d_ws;
    unsigned short* Bmat = (unsigned short*)ws;          // 131072 B
    float* m2    = (float*)(ws + 131072);                // 512 B
    float* ivbuf = (float*)(ws + 131584);                // 2048 B
    float* coef  = (float*)(ws + 133632);                // 4 B

    gs_prep<<<LDIM, 64, 0, stream>>>(means, var, Bmat, m2, ivbuf, coef);
    gs_main<<<MTOT / TM, 256, 0, stream>>>(emb, Bmat, m2, ivbuf, coef, out);
}